// Round 1
// baseline (2118.783 us; speedup 1.0000x reference)
//
#include <hip/hip_runtime.h>
#include <hip/hip_bf16.h>
#include <math.h>

#define NN 100000
#define NE 3200000
#define NF 256
#define NH 128
#define NC 40
#define BN_EPS 1e-5f

// ---------------- init: deg=1 (self loop), count=0, sums=0 ----------------
__global__ __launch_bounds__(256) void k_init(float* deg, int* count, float* sums) {
    int i = blockIdx.x * 256 + threadIdx.x;
    if (i < NN) { deg[i] = 1.0f; count[i] = 0; }
    if (i < 3 * 1024) sums[i] = 0.0f;
}

// ---------------- edge pass: degree (weighted) + in-degree histogram ----------------
__global__ __launch_bounds__(256) void k_edge(const int* __restrict__ ei, const float* __restrict__ ew,
                                              float* __restrict__ deg, int* __restrict__ count) {
    int e = blockIdx.x * 256 + threadIdx.x;
    if (e >= NE) return;
    int d = ei[NE + e];
    atomicAdd(&deg[d], ew[e]);
    atomicAdd(&count[d], 1);
}

// ---------------- dinv = rsqrt(deg) in place (deg >= 1 always) ----------------
__global__ __launch_bounds__(256) void k_dinv(float* deg) {
    int i = blockIdx.x * 256 + threadIdx.x;
    if (i < NN) deg[i] = rsqrtf(deg[i]);
}

// ---------------- single-block exclusive scan of count -> rowptr, fill ----------------
__global__ __launch_bounds__(1024) void k_scan(const int* __restrict__ count,
                                               int* __restrict__ rowptr, int* __restrict__ fill) {
    __shared__ int wsum[16];
    __shared__ int s_carry;
    int t = threadIdx.x;
    int lane = t & 63, wid = t >> 6;
    if (t == 0) s_carry = 0;
    __syncthreads();
    for (int base = 0; base < NN; base += 1024) {
        int i = base + t;
        int v = (i < NN) ? count[i] : 0;
        int x = v;
#pragma unroll
        for (int off = 1; off < 64; off <<= 1) {
            int y = __shfl_up(x, off);
            if (lane >= off) x += y;
        }
        if (lane == 63) wsum[wid] = x;
        __syncthreads();
        if (wid == 0 && lane < 16) {
            int s = wsum[lane];
#pragma unroll
            for (int off = 1; off < 16; off <<= 1) {
                int y = __shfl_up(s, off);
                if (lane >= off) s += y;
            }
            wsum[lane] = s;
        }
        __syncthreads();
        int woff = (wid > 0) ? wsum[wid - 1] : 0;
        int incl = x + woff;
        int carry = s_carry;
        int start = carry + incl - v;
        if (i < NN) { rowptr[i] = start; fill[i] = start; }
        __syncthreads();
        if (t == 1023) s_carry = carry + incl;
        __syncthreads();
    }
    if (t == 0) rowptr[NN] = s_carry;
}

// ---------------- scatter edges into CSR, norm computed inline ----------------
__global__ __launch_bounds__(256) void k_scatter(const int* __restrict__ ei, const float* __restrict__ ew,
                                                 const float* __restrict__ dinv, int* __restrict__ fill,
                                                 int* __restrict__ col, float* __restrict__ wval) {
    int e = blockIdx.x * 256 + threadIdx.x;
    if (e >= NE) return;
    int s = ei[e], d = ei[NE + e];
    float nv = dinv[s] * ew[e] * dinv[d];
    int pos = atomicAdd(&fill[d], 1);
    col[pos] = s;
    wval[pos] = nv;
}

// ---------------- tiled f32 GEMM: out[NN,128] = H[NN,K](ld=ldh) @ W[K,128] ----------------
template <int K>
__global__ __launch_bounds__(256) void k_gemm(const float* __restrict__ H, int ldh,
                                              const float* __restrict__ W, float* __restrict__ out) {
    __shared__ float As[64][36];
    __shared__ float Bs[32][128];
    int t = threadIdx.x;
    int xcol = (t & 31) << 2;   // 0..124 step 4
    int yrow = t >> 5;          // 0..7
    int rowbase = blockIdx.x * 64;
    float acc[8][4];
#pragma unroll
    for (int i = 0; i < 8; i++)
#pragma unroll
        for (int j = 0; j < 4; j++) acc[i][j] = 0.f;

    for (int kc = 0; kc < K; kc += 32) {
#pragma unroll
        for (int s = 0; s < 2; s++) {
            int idx = t + s * 256;
            int r = idx >> 3, kk = (idx & 7) << 2;
            int gr = rowbase + r;
            float4 v = make_float4(0.f, 0.f, 0.f, 0.f);
            if (gr < NN) v = *(const float4*)&H[(size_t)gr * ldh + kc + kk];
            *(float4*)&As[r][kk] = v;
        }
#pragma unroll
        for (int s = 0; s < 4; s++) {
            int idx = t + s * 256;
            int k = idx >> 5, c = (idx & 31) << 2;
            *(float4*)&Bs[k][c] = *(const float4*)&W[(size_t)(kc + k) * NH + c];
        }
        __syncthreads();
#pragma unroll
        for (int kk = 0; kk < 32; kk += 4) {
            float4 a[8];
#pragma unroll
            for (int i = 0; i < 8; i++) a[i] = *(const float4*)&As[yrow + i * 8][kk];
#pragma unroll
            for (int q = 0; q < 4; q++) {
                float4 b = *(const float4*)&Bs[kk + q][xcol];
#pragma unroll
                for (int i = 0; i < 8; i++) {
                    float av = (q == 0) ? a[i].x : (q == 1) ? a[i].y : (q == 2) ? a[i].z : a[i].w;
                    acc[i][0] = fmaf(av, b.x, acc[i][0]);
                    acc[i][1] = fmaf(av, b.y, acc[i][1]);
                    acc[i][2] = fmaf(av, b.z, acc[i][2]);
                    acc[i][3] = fmaf(av, b.w, acc[i][3]);
                }
            }
        }
        __syncthreads();
    }
#pragma unroll
    for (int i = 0; i < 8; i++) {
        int gr = rowbase + yrow + i * 8;
        if (gr < NN)
            *(float4*)&out[(size_t)gr * NH + xcol] =
                make_float4(acc[i][0], acc[i][1], acc[i][2], acc[i][3]);
    }
}

// ---------------- CSR gather-aggregate + self loop + bias + relu; writes stride-384 ----------------
__global__ __launch_bounds__(256) void k_agg(const float* __restrict__ lin, const float* __restrict__ dinv,
                                             const int* __restrict__ rowptr, const int* __restrict__ col,
                                             const float* __restrict__ wval, const float* __restrict__ bias,
                                             float* __restrict__ outp, int do_relu) {
    int t = threadIdx.x;
    int node = blockIdx.x * 4 + (t >> 6);
    if (node >= NN) return;
    int c = (t & 63) << 1;  // channel pair
    float di = dinv[node];
    float2 sv = *(const float2*)&lin[(size_t)node * NH + c];
    float a0 = fmaf(sv.x, di * di, bias[c]);
    float a1 = fmaf(sv.y, di * di, bias[c + 1]);
    int beg = rowptr[node], end = rowptr[node + 1];
    for (int j = beg; j < end; j++) {
        int s = col[j];
        float w = wval[j];
        float2 v = *(const float2*)&lin[(size_t)s * NH + c];
        a0 = fmaf(v.x, w, a0);
        a1 = fmaf(v.y, w, a1);
    }
    if (do_relu) { a0 = fmaxf(a0, 0.f); a1 = fmaxf(a1, 0.f); }
    *(float2*)&outp[(size_t)node * 384 + c] = make_float2(a0, a1);
}

// ---------------- BN stats: per-channel sum & sumsq over stride-384 matrix ----------------
__global__ __launch_bounds__(256) void k_stats(const float* __restrict__ pre, float* __restrict__ sums) {
    int t = threadIdx.x;
    int c = t & 127, h = t >> 7;
    float s = 0.f, s2 = 0.f;
    for (int r = blockIdx.x * 2 + h; r < NN; r += gridDim.x * 2) {
        float v = pre[(size_t)r * 384 + c];
        s += v;
        s2 = fmaf(v, v, s2);
    }
    __shared__ float ls[256], ls2[256];
    ls[t] = s; ls2[t] = s2;
    __syncthreads();
    if (t < 128) {
        atomicAdd(&sums[c], ls[t] + ls[t + 128]);
        atomicAdd(&sums[NH + c], ls2[t] + ls2[t + 128]);
    }
}

// ---------------- finalize BN: scale/shift per channel ----------------
__global__ void k_bnfinal(float* __restrict__ sums, const float* __restrict__ g,
                          const float* __restrict__ beta) {
    int c = threadIdx.x;
    if (c < NH) {
        float m = sums[c] * (1.0f / NN);
        float v = sums[NH + c] * (1.0f / NN) - m * m;
        float rstd = rsqrtf(v + BN_EPS);
        float sc = g[c] * rstd;
        sums[256 + c] = sc;
        sums[384 + c] = beta[c] - m * sc;
    }
}

// ---------------- apply BN affine in place (stride-384 region) ----------------
__global__ __launch_bounds__(256) void k_bnapply(float* __restrict__ pre, const float* __restrict__ sums) {
    int idx = blockIdx.x * 256 + threadIdx.x;  // NN*64 float2's
    if (idx >= NN * 64) return;
    int n = idx >> 6, cp = (idx & 63) << 1;
    float2 sc = *(const float2*)&sums[256 + cp];
    float2 sh = *(const float2*)&sums[384 + cp];
    float2 v = *(float2*)&pre[(size_t)n * 384 + cp];
    v.x = fmaf(v.x, sc.x, sh.x);
    v.y = fmaf(v.y, sc.y, sh.y);
    *(float2*)&pre[(size_t)n * 384 + cp] = v;
}

// ---------------- final linear [NN,384]@[384,40] + softmax ----------------
__global__ __launch_bounds__(256) void k_final(const float* __restrict__ embed,
                                               const float* __restrict__ linW,
                                               const float* __restrict__ linb,
                                               float* __restrict__ logits, float* __restrict__ probs) {
    __shared__ __hip_bfloat16 Wl[384 * NC];  // 30720 B
    __shared__ float rowbuf[4][384];
    int t = threadIdx.x;
    for (int i = t; i < 384 * NC; i += 256) Wl[i] = __float2bfloat16(linW[i]);
    __syncthreads();
    int wid = t >> 6, l = t & 63;
    float bb = (l < NC) ? linb[l] : 0.f;
    int per = gridDim.x * 4;
    int iters = (NN + per - 1) / per;
    for (int it = 0; it < iters; it++) {
        int n = (it * gridDim.x + blockIdx.x) * 4 + wid;
        bool act = n < NN;
        if (act) {
#pragma unroll
            for (int j = 0; j < 6; j++)
                rowbuf[wid][l + j * 64] = embed[(size_t)n * 384 + l + j * 64];
        }
        __syncthreads();
        float acc = bb;
        if (act && l < NC) {
            for (int k = 0; k < 384; k++)
                acc = fmaf(rowbuf[wid][k], __bfloat162float(Wl[k * NC + l]), acc);
        }
        float mval = (act && l < NC) ? acc : -3.4e38f;
#pragma unroll
        for (int off = 32; off >= 1; off >>= 1) mval = fmaxf(mval, __shfl_xor(mval, off));
        float p = (act && l < NC) ? __expf(acc - mval) : 0.f;
        float sum = p;
#pragma unroll
        for (int off = 32; off >= 1; off >>= 1) sum += __shfl_xor(sum, off);
        if (act && l < NC) {
            logits[(size_t)n * NC + l] = acc;
            probs[(size_t)n * NC + l] = p / sum;
        }
        __syncthreads();
    }
}

extern "C" void kernel_launch(void* const* d_in, const int* in_sizes, int n_in,
                              void* d_out, int out_size, void* d_ws, size_t ws_size,
                              hipStream_t stream) {
    const float* x    = (const float*)d_in[0];
    const int*   ei   = (const int*)d_in[1];
    const float* ew   = (const float*)d_in[2];
    const float* W1   = (const float*)d_in[3];
    const float* b1   = (const float*)d_in[4];
    const float* g1   = (const float*)d_in[5];
    const float* be1  = (const float*)d_in[6];
    const float* W2   = (const float*)d_in[7];
    const float* b2   = (const float*)d_in[8];
    const float* g2   = (const float*)d_in[9];
    const float* be2  = (const float*)d_in[10];
    const float* W3   = (const float*)d_in[11];
    const float* b3   = (const float*)d_in[12];
    const float* g3   = (const float*)d_in[13];
    const float* be3  = (const float*)d_in[14];
    const float* linW = (const float*)d_in[15];
    const float* linb = (const float*)d_in[16];

    float* out    = (float*)d_out;
    float* logits = out;
    float* probs  = out + (size_t)NN * NC;
    float* embed  = out + (size_t)2 * NN * NC;

    char* ws = (char*)d_ws;
    size_t off = 0;
    auto alloc = [&](size_t bytes) -> char* {
        char* p = ws + off;
        off = (off + bytes + 255) & ~(size_t)255;
        return p;
    };
    float* deg    = (float*)alloc((size_t)NN * 4);
    int*   count  = (int*)alloc((size_t)NN * 4);
    int*   rowptr = (int*)alloc((size_t)(NN + 1) * 4);
    int*   fill   = (int*)alloc((size_t)NN * 4);
    int*   col    = (int*)alloc((size_t)NE * 4);
    float* wval   = (float*)alloc((size_t)NE * 4);
    float* lin    = (float*)alloc((size_t)NN * NH * 4);
    float* sums   = (float*)alloc(3 * 1024 * 4);
    (void)ws_size; (void)in_sizes; (void)n_in; (void)out_size;

    int gN = (NN + 255) / 256;
    int gE = (NE + 255) / 256;
    int gG = (NN + 63) / 64;
    int gA = (NN + 3) / 4;
    int gB = (NN * 64 + 255) / 256;

    k_init<<<gN, 256, 0, stream>>>(deg, count, sums);
    k_edge<<<gE, 256, 0, stream>>>(ei, ew, deg, count);
    k_dinv<<<gN, 256, 0, stream>>>(deg);
    k_scan<<<1, 1024, 0, stream>>>(count, rowptr, fill);
    k_scatter<<<gE, 256, 0, stream>>>(ei, ew, deg, fill, col, wval);

    // layer 1
    k_gemm<NF><<<gG, 256, 0, stream>>>(x, NF, W1, lin);
    k_agg<<<gA, 256, 0, stream>>>(lin, deg, rowptr, col, wval, b1, embed + 0, 1);
    k_stats<<<1024, 256, 0, stream>>>(embed + 0, sums + 0);
    k_bnfinal<<<1, 128, 0, stream>>>(sums + 0, g1, be1);
    k_bnapply<<<gB, 256, 0, stream>>>(embed + 0, sums + 0);
    // layer 2
    k_gemm<NH><<<gG, 256, 0, stream>>>(embed + 0, 384, W2, lin);
    k_agg<<<gA, 256, 0, stream>>>(lin, deg, rowptr, col, wval, b2, embed + 128, 1);
    k_stats<<<1024, 256, 0, stream>>>(embed + 128, sums + 1024);
    k_bnfinal<<<1, 128, 0, stream>>>(sums + 1024, g2, be2);
    k_bnapply<<<gB, 256, 0, stream>>>(embed + 128, sums + 1024);
    // layer 3 (no relu)
    k_gemm<NH><<<gG, 256, 0, stream>>>(embed + 128, 384, W3, lin);
    k_agg<<<gA, 256, 0, stream>>>(lin, deg, rowptr, col, wval, b3, embed + 256, 0);
    k_stats<<<1024, 256, 0, stream>>>(embed + 256, sums + 2048);
    k_bnfinal<<<1, 128, 0, stream>>>(sums + 2048, g3, be3);
    k_bnapply<<<gB, 256, 0, stream>>>(embed + 256, sums + 2048);
    // final linear + softmax
    k_final<<<2048, 256, 0, stream>>>(embed, linW, linb, logits, probs);
}

// Round 2
// 1705.715 us; speedup vs baseline: 1.2422x; 1.2422x over previous
//
#include <hip/hip_runtime.h>
#include <hip/hip_bf16.h>
#include <math.h>

#define NN 100000
#define NE 3200000
#define NF 256
#define NH 128
#define NC 40
#define BN_EPS 1e-5f

// ---------------- init: deg=1 (self loop), count=0, sums=0 ----------------
__global__ __launch_bounds__(256) void k_init(float* deg, int* count, float* sums) {
    int i = blockIdx.x * 256 + threadIdx.x;
    if (i < NN) { deg[i] = 1.0f; count[i] = 0; }
    if (i < 3 * 1024) sums[i] = 0.0f;
}

// ---------------- edge pass: degree (weighted) + in-degree histogram ----------------
__global__ __launch_bounds__(256) void k_edge(const int* __restrict__ ei, const float* __restrict__ ew,
                                              float* __restrict__ deg, int* __restrict__ count) {
    int e = blockIdx.x * 256 + threadIdx.x;
    if (e >= NE) return;
    int d = ei[NE + e];
    atomicAdd(&deg[d], ew[e]);
    atomicAdd(&count[d], 1);
}

// ---------------- dinv = rsqrt(deg) in place (deg >= 1 always) ----------------
__global__ __launch_bounds__(256) void k_dinv(float* deg) {
    int i = blockIdx.x * 256 + threadIdx.x;
    if (i < NN) deg[i] = rsqrtf(deg[i]);
}

// ---------------- single-block exclusive scan of count -> rowptr, fill ----------------
__global__ __launch_bounds__(1024) void k_scan(const int* __restrict__ count,
                                               int* __restrict__ rowptr, int* __restrict__ fill) {
    __shared__ int wsum[16];
    __shared__ int s_carry;
    int t = threadIdx.x;
    int lane = t & 63, wid = t >> 6;
    if (t == 0) s_carry = 0;
    __syncthreads();
    for (int base = 0; base < NN; base += 1024) {
        int i = base + t;
        int v = (i < NN) ? count[i] : 0;
        int x = v;
#pragma unroll
        for (int off = 1; off < 64; off <<= 1) {
            int y = __shfl_up(x, off);
            if (lane >= off) x += y;
        }
        if (lane == 63) wsum[wid] = x;
        __syncthreads();
        if (wid == 0 && lane < 16) {
            int s = wsum[lane];
#pragma unroll
            for (int off = 1; off < 16; off <<= 1) {
                int y = __shfl_up(s, off);
                if (lane >= off) s += y;
            }
            wsum[lane] = s;
        }
        __syncthreads();
        int woff = (wid > 0) ? wsum[wid - 1] : 0;
        int incl = x + woff;
        int carry = s_carry;
        int start = carry + incl - v;
        if (i < NN) { rowptr[i] = start; fill[i] = start; }
        __syncthreads();
        if (t == 1023) s_carry = carry + incl;
        __syncthreads();
    }
    if (t == 0) rowptr[NN] = s_carry;
}

// ---------------- scatter edges into CSR (packed col+norm), norm inline ----------------
__global__ __launch_bounds__(256) void k_scatter(const int* __restrict__ ei, const float* __restrict__ ew,
                                                 const float* __restrict__ dinv, int* __restrict__ fill,
                                                 int2* __restrict__ cw) {
    int e = blockIdx.x * 256 + threadIdx.x;
    if (e >= NE) return;
    int s = ei[e], d = ei[NE + e];
    float nv = dinv[s] * ew[e] * dinv[d];
    int pos = atomicAdd(&fill[d], 1);
    cw[pos] = make_int2(s, __float_as_int(nv));
}

// ---------------- tiled f32 GEMM: out_bf16[NN,128] = H[NN,K](ld=ldh) @ W[K,128] ----------------
template <int K>
__global__ __launch_bounds__(256) void k_gemm(const float* __restrict__ H, int ldh,
                                              const float* __restrict__ W,
                                              __hip_bfloat16* __restrict__ out) {
    __shared__ float As[64][36];
    __shared__ float Bs[32][128];
    int t = threadIdx.x;
    int xcol = (t & 31) << 2;   // 0..124 step 4
    int yrow = t >> 5;          // 0..7
    int rowbase = blockIdx.x * 64;
    float acc[8][4];
#pragma unroll
    for (int i = 0; i < 8; i++)
#pragma unroll
        for (int j = 0; j < 4; j++) acc[i][j] = 0.f;

    for (int kc = 0; kc < K; kc += 32) {
#pragma unroll
        for (int s = 0; s < 2; s++) {
            int idx = t + s * 256;
            int r = idx >> 3, kk = (idx & 7) << 2;
            int gr = rowbase + r;
            float4 v = make_float4(0.f, 0.f, 0.f, 0.f);
            if (gr < NN) v = *(const float4*)&H[(size_t)gr * ldh + kc + kk];
            *(float4*)&As[r][kk] = v;
        }
#pragma unroll
        for (int s = 0; s < 4; s++) {
            int idx = t + s * 256;
            int k = idx >> 5, c = (idx & 31) << 2;
            *(float4*)&Bs[k][c] = *(const float4*)&W[(size_t)(kc + k) * NH + c];
        }
        __syncthreads();
#pragma unroll
        for (int kk = 0; kk < 32; kk += 4) {
            float4 a[8];
#pragma unroll
            for (int i = 0; i < 8; i++) a[i] = *(const float4*)&As[yrow + i * 8][kk];
#pragma unroll
            for (int q = 0; q < 4; q++) {
                float4 b = *(const float4*)&Bs[kk + q][xcol];
#pragma unroll
                for (int i = 0; i < 8; i++) {
                    float av = (q == 0) ? a[i].x : (q == 1) ? a[i].y : (q == 2) ? a[i].z : a[i].w;
                    acc[i][0] = fmaf(av, b.x, acc[i][0]);
                    acc[i][1] = fmaf(av, b.y, acc[i][1]);
                    acc[i][2] = fmaf(av, b.z, acc[i][2]);
                    acc[i][3] = fmaf(av, b.w, acc[i][3]);
                }
            }
        }
        __syncthreads();
    }
#pragma unroll
    for (int i = 0; i < 8; i++) {
        int gr = rowbase + yrow + i * 8;
        if (gr < NN) {
            union { ushort4 u; __hip_bfloat16 h[4]; } o;
            o.h[0] = __float2bfloat16(acc[i][0]);
            o.h[1] = __float2bfloat16(acc[i][1]);
            o.h[2] = __float2bfloat16(acc[i][2]);
            o.h[3] = __float2bfloat16(acc[i][3]);
            *(ushort4*)&out[(size_t)gr * NH + xcol] = o.u;
        }
    }
}

__device__ __forceinline__ float2 bf2_unpack(unsigned int v) {
    return make_float2(__uint_as_float(v << 16), __uint_as_float(v & 0xffff0000u));
}

// ---------------- CSR gather-aggregate (bf16 lin) + self loop + bias + relu; writes stride-384 ----------------
__global__ __launch_bounds__(256) void k_agg(const unsigned int* __restrict__ linb,
                                             const float* __restrict__ dinv,
                                             const int* __restrict__ rowptr, const int2* __restrict__ cw,
                                             const float* __restrict__ bias,
                                             float* __restrict__ outp, int do_relu) {
    int t = threadIdx.x;
    int node = blockIdx.x * 4 + (t >> 6);
    if (node >= NN) return;
    int ch = t & 63;          // packed-pair index: channels 2*ch, 2*ch+1
    int c = ch << 1;
    float di = dinv[node];
    float2 sv = bf2_unpack(linb[(size_t)node * 64 + ch]);
    float a0 = fmaf(sv.x, di * di, bias[c]);
    float a1 = fmaf(sv.y, di * di, bias[c + 1]);
    int beg = rowptr[node], end = rowptr[node + 1];
    int j = beg;
    for (; j + 1 < end; j += 2) {
        int2 p0 = cw[j];
        int2 p1 = cw[j + 1];
        unsigned int v0 = linb[(size_t)p0.x * 64 + ch];
        unsigned int v1 = linb[(size_t)p1.x * 64 + ch];
        float w0 = __int_as_float(p0.y);
        float w1 = __int_as_float(p1.y);
        float2 f0 = bf2_unpack(v0);
        float2 f1 = bf2_unpack(v1);
        a0 = fmaf(f0.x, w0, a0);
        a1 = fmaf(f0.y, w0, a1);
        a0 = fmaf(f1.x, w1, a0);
        a1 = fmaf(f1.y, w1, a1);
    }
    if (j < end) {
        int2 p = cw[j];
        unsigned int v = linb[(size_t)p.x * 64 + ch];
        float w = __int_as_float(p.y);
        float2 f = bf2_unpack(v);
        a0 = fmaf(f.x, w, a0);
        a1 = fmaf(f.y, w, a1);
    }
    if (do_relu) { a0 = fmaxf(a0, 0.f); a1 = fmaxf(a1, 0.f); }
    *(float2*)&outp[(size_t)node * 384 + c] = make_float2(a0, a1);
}

// ---------------- BN stats: per-channel sum & sumsq over stride-384 matrix ----------------
__global__ __launch_bounds__(256) void k_stats(const float* __restrict__ pre, float* __restrict__ sums) {
    int t = threadIdx.x;
    int c = t & 127, h = t >> 7;
    float s = 0.f, s2 = 0.f;
    for (int r = blockIdx.x * 2 + h; r < NN; r += gridDim.x * 2) {
        float v = pre[(size_t)r * 384 + c];
        s += v;
        s2 = fmaf(v, v, s2);
    }
    __shared__ float ls[256], ls2[256];
    ls[t] = s; ls2[t] = s2;
    __syncthreads();
    if (t < 128) {
        atomicAdd(&sums[c], ls[t] + ls[t + 128]);
        atomicAdd(&sums[NH + c], ls2[t] + ls2[t + 128]);
    }
}

// ---------------- finalize BN: scale/shift per channel ----------------
__global__ void k_bnfinal(float* __restrict__ sums, const float* __restrict__ g,
                          const float* __restrict__ beta) {
    int c = threadIdx.x;
    if (c < NH) {
        float m = sums[c] * (1.0f / NN);
        float v = sums[NH + c] * (1.0f / NN) - m * m;
        float rstd = rsqrtf(v + BN_EPS);
        float sc = g[c] * rstd;
        sums[256 + c] = sc;
        sums[384 + c] = beta[c] - m * sc;
    }
}

// ---------------- apply BN affine in place (stride-384 region) ----------------
__global__ __launch_bounds__(256) void k_bnapply(float* __restrict__ pre, const float* __restrict__ sums) {
    int idx = blockIdx.x * 256 + threadIdx.x;  // NN*64 float2's
    if (idx >= NN * 64) return;
    int n = idx >> 6, cp = (idx & 63) << 1;
    float2 sc = *(const float2*)&sums[256 + cp];
    float2 sh = *(const float2*)&sums[384 + cp];
    float2 v = *(float2*)&pre[(size_t)n * 384 + cp];
    v.x = fmaf(v.x, sc.x, sh.x);
    v.y = fmaf(v.y, sc.y, sh.y);
    *(float2*)&pre[(size_t)n * 384 + cp] = v;
}

// ---------------- final linear [NN,384]@[384,40] + softmax ----------------
// W staged in LDS as k-pairs: Wp[k2*NC + c] packs (k=2*k2 lo, k=2*k2+1 hi) bf16.
// Embed row read via wave-uniform global float4 broadcast loads (no LDS rowbuf, no sync in loop).
__global__ __launch_bounds__(256) void k_final(const float* __restrict__ embed,
                                               const float* __restrict__ linW,
                                               const float* __restrict__ linb,
                                               float* __restrict__ logits, float* __restrict__ probs) {
    __shared__ unsigned int Wp[192 * NC];  // 30720 B
    int t = threadIdx.x;
    for (int i = t; i < 192 * NC; i += 256) {
        int k2 = i / NC, c = i - k2 * NC;
        unsigned int lo = ((unsigned int)__hip_bfloat16_raw(__float2bfloat16(linW[(2 * k2) * NC + c])).x);
        unsigned int hi = ((unsigned int)__hip_bfloat16_raw(__float2bfloat16(linW[(2 * k2 + 1) * NC + c])).x);
        Wp[i] = lo | (hi << 16);
    }
    __syncthreads();
    int wid = t >> 6, l = t & 63;
    float bb = (l < NC) ? linb[l] : 0.f;
    int stride = gridDim.x * 4;
    for (int n = blockIdx.x * 4 + wid; n < NN; n += stride) {
        const float4* row = (const float4*)&embed[(size_t)n * 384];
        float acc = bb;
        if (l < NC) {
            for (int k4 = 0; k4 < 96; k4 += 1) {
                float4 a = row[k4];  // wave-uniform address -> broadcast
                int k2 = k4 * 2;
                float2 w0 = bf2_unpack(Wp[k2 * NC + l]);
                float2 w1 = bf2_unpack(Wp[(k2 + 1) * NC + l]);
                acc = fmaf(a.x, w0.x, acc);
                acc = fmaf(a.y, w0.y, acc);
                acc = fmaf(a.z, w1.x, acc);
                acc = fmaf(a.w, w1.y, acc);
            }
        }
        float mval = (l < NC) ? acc : -3.4e38f;
#pragma unroll
        for (int off = 32; off >= 1; off >>= 1) mval = fmaxf(mval, __shfl_xor(mval, off));
        float p = (l < NC) ? __expf(acc - mval) : 0.f;
        float sum = p;
#pragma unroll
        for (int off = 32; off >= 1; off >>= 1) sum += __shfl_xor(sum, off);
        if (l < NC) {
            logits[(size_t)n * NC + l] = acc;
            probs[(size_t)n * NC + l] = p / sum;
        }
    }
}

extern "C" void kernel_launch(void* const* d_in, const int* in_sizes, int n_in,
                              void* d_out, int out_size, void* d_ws, size_t ws_size,
                              hipStream_t stream) {
    const float* x    = (const float*)d_in[0];
    const int*   ei   = (const int*)d_in[1];
    const float* ew   = (const float*)d_in[2];
    const float* W1   = (const float*)d_in[3];
    const float* b1   = (const float*)d_in[4];
    const float* g1   = (const float*)d_in[5];
    const float* be1  = (const float*)d_in[6];
    const float* W2   = (const float*)d_in[7];
    const float* b2   = (const float*)d_in[8];
    const float* g2   = (const float*)d_in[9];
    const float* be2  = (const float*)d_in[10];
    const float* W3   = (const float*)d_in[11];
    const float* b3   = (const float*)d_in[12];
    const float* g3   = (const float*)d_in[13];
    const float* be3  = (const float*)d_in[14];
    const float* linW = (const float*)d_in[15];
    const float* linb = (const float*)d_in[16];

    float* out    = (float*)d_out;
    float* logits = out;
    float* probs  = out + (size_t)NN * NC;
    float* embed  = out + (size_t)2 * NN * NC;

    char* ws = (char*)d_ws;
    size_t off = 0;
    auto alloc = [&](size_t bytes) -> char* {
        char* p = ws + off;
        off = (off + bytes + 255) & ~(size_t)255;
        return p;
    };
    float* deg    = (float*)alloc((size_t)NN * 4);
    int*   count  = (int*)alloc((size_t)NN * 4);
    int*   rowptr = (int*)alloc((size_t)(NN + 1) * 4);
    int*   fill   = (int*)alloc((size_t)NN * 4);
    int2*  cw     = (int2*)alloc((size_t)NE * 8);
    __hip_bfloat16* lin = (__hip_bfloat16*)alloc((size_t)NN * NH * 2);
    float* sums   = (float*)alloc(3 * 1024 * 4);
    (void)ws_size; (void)in_sizes; (void)n_in; (void)out_size;

    int gN = (NN + 255) / 256;
    int gE = (NE + 255) / 256;
    int gG = (NN + 63) / 64;
    int gA = (NN + 3) / 4;
    int gB = (NN * 64 + 255) / 256;

    k_init<<<gN, 256, 0, stream>>>(deg, count, sums);
    k_edge<<<gE, 256, 0, stream>>>(ei, ew, deg, count);
    k_dinv<<<gN, 256, 0, stream>>>(deg);
    k_scan<<<1, 1024, 0, stream>>>(count, rowptr, fill);
    k_scatter<<<gE, 256, 0, stream>>>(ei, ew, deg, fill, cw);

    // layer 1
    k_gemm<NF><<<gG, 256, 0, stream>>>(x, NF, W1, lin);
    k_agg<<<gA, 256, 0, stream>>>((const unsigned int*)lin, deg, rowptr, cw, b1, embed + 0, 1);
    k_stats<<<1024, 256, 0, stream>>>(embed + 0, sums + 0);
    k_bnfinal<<<1, 128, 0, stream>>>(sums + 0, g1, be1);
    k_bnapply<<<gB, 256, 0, stream>>>(embed + 0, sums + 0);
    // layer 2
    k_gemm<NH><<<gG, 256, 0, stream>>>(embed + 0, 384, W2, lin);
    k_agg<<<gA, 256, 0, stream>>>((const unsigned int*)lin, deg, rowptr, cw, b2, embed + 128, 1);
    k_stats<<<1024, 256, 0, stream>>>(embed + 128, sums + 1024);
    k_bnfinal<<<1, 128, 0, stream>>>(sums + 1024, g2, be2);
    k_bnapply<<<gB, 256, 0, stream>>>(embed + 128, sums + 1024);
    // layer 3 (no relu)
    k_gemm<NH><<<gG, 256, 0, stream>>>(embed + 128, 384, W3, lin);
    k_agg<<<gA, 256, 0, stream>>>((const unsigned int*)lin, deg, rowptr, cw, b3, embed + 256, 0);
    k_stats<<<1024, 256, 0, stream>>>(embed + 256, sums + 2048);
    k_bnfinal<<<1, 128, 0, stream>>>(sums + 2048, g3, be3);
    k_bnapply<<<gB, 256, 0, stream>>>(embed + 256, sums + 2048);
    // final linear + softmax
    k_final<<<1024, 256, 0, stream>>>(embed, linW, linb, logits, probs);
}

// Round 3
// 1528.688 us; speedup vs baseline: 1.3860x; 1.1158x over previous
//
#include <hip/hip_runtime.h>
#include <hip/hip_bf16.h>
#include <math.h>

#define NN 100000
#define NE 3200000
#define NF 256
#define NH 128
#define NC 40
#define BN_EPS 1e-5f

typedef __attribute__((ext_vector_type(8))) short bf16x8;
typedef __attribute__((ext_vector_type(4))) float f32x4;

// ---------------- init: deg=1 (self loop), count=0, sums=0 ----------------
__global__ __launch_bounds__(256) void k_init(float* deg, int* count, float* sums) {
    int i = blockIdx.x * 256 + threadIdx.x;
    if (i < NN) { deg[i] = 1.0f; count[i] = 0; }
    if (i < 3 * 1024) sums[i] = 0.0f;
}

// ---------------- edge pass: degree (weighted) + in-degree histogram ----------------
__global__ __launch_bounds__(256) void k_edge(const int* __restrict__ ei, const float* __restrict__ ew,
                                              float* __restrict__ deg, int* __restrict__ count) {
    int e = blockIdx.x * 256 + threadIdx.x;
    if (e >= NE) return;
    int d = ei[NE + e];
    atomicAdd(&deg[d], ew[e]);
    atomicAdd(&count[d], 1);
}

// ---------------- dinv = rsqrt(deg) in place (deg >= 1 always) ----------------
__global__ __launch_bounds__(256) void k_dinv(float* deg) {
    int i = blockIdx.x * 256 + threadIdx.x;
    if (i < NN) deg[i] = rsqrtf(deg[i]);
}

// ---------------- single-block exclusive scan of count -> rowptr, fill ----------------
__global__ __launch_bounds__(1024) void k_scan(const int* __restrict__ count,
                                               int* __restrict__ rowptr, int* __restrict__ fill) {
    __shared__ int wsum[16];
    __shared__ int s_carry;
    int t = threadIdx.x;
    int lane = t & 63, wid = t >> 6;
    if (t == 0) s_carry = 0;
    __syncthreads();
    for (int base = 0; base < NN; base += 1024) {
        int i = base + t;
        int v = (i < NN) ? count[i] : 0;
        int x = v;
#pragma unroll
        for (int off = 1; off < 64; off <<= 1) {
            int y = __shfl_up(x, off);
            if (lane >= off) x += y;
        }
        if (lane == 63) wsum[wid] = x;
        __syncthreads();
        if (wid == 0 && lane < 16) {
            int s = wsum[lane];
#pragma unroll
            for (int off = 1; off < 16; off <<= 1) {
                int y = __shfl_up(s, off);
                if (lane >= off) s += y;
            }
            wsum[lane] = s;
        }
        __syncthreads();
        int woff = (wid > 0) ? wsum[wid - 1] : 0;
        int incl = x + woff;
        int carry = s_carry;
        int start = carry + incl - v;
        if (i < NN) { rowptr[i] = start; fill[i] = start; }
        __syncthreads();
        if (t == 1023) s_carry = carry + incl;
        __syncthreads();
    }
    if (t == 0) rowptr[NN] = s_carry;
}

// ---------------- scatter edges into CSR (packed col+norm), norm inline ----------------
__global__ __launch_bounds__(256) void k_scatter(const int* __restrict__ ei, const float* __restrict__ ew,
                                                 const float* __restrict__ dinv, int* __restrict__ fill,
                                                 int2* __restrict__ cw) {
    int e = blockIdx.x * 256 + threadIdx.x;
    if (e >= NE) return;
    int s = ei[e], d = ei[NE + e];
    float nv = dinv[s] * ew[e] * dinv[d];
    int pos = atomicAdd(&fill[d], 1);
    cw[pos] = make_int2(s, __float_as_int(nv));
}

// ---------------- tiled f32 GEMM: out_bf16[NN,128] = H[NN,K](ld=ldh) @ W[K,128] ----------------
template <int K>
__global__ __launch_bounds__(256) void k_gemm(const float* __restrict__ H, int ldh,
                                              const float* __restrict__ W,
                                              __hip_bfloat16* __restrict__ out) {
    __shared__ float As[64][36];
    __shared__ float Bs[32][128];
    int t = threadIdx.x;
    int xcol = (t & 31) << 2;   // 0..124 step 4
    int yrow = t >> 5;          // 0..7
    int rowbase = blockIdx.x * 64;
    float acc[8][4];
#pragma unroll
    for (int i = 0; i < 8; i++)
#pragma unroll
        for (int j = 0; j < 4; j++) acc[i][j] = 0.f;

    for (int kc = 0; kc < K; kc += 32) {
#pragma unroll
        for (int s = 0; s < 2; s++) {
            int idx = t + s * 256;
            int r = idx >> 3, kk = (idx & 7) << 2;
            int gr = rowbase + r;
            float4 v = make_float4(0.f, 0.f, 0.f, 0.f);
            if (gr < NN) v = *(const float4*)&H[(size_t)gr * ldh + kc + kk];
            *(float4*)&As[r][kk] = v;
        }
#pragma unroll
        for (int s = 0; s < 4; s++) {
            int idx = t + s * 256;
            int k = idx >> 5, c = (idx & 31) << 2;
            *(float4*)&Bs[k][c] = *(const float4*)&W[(size_t)(kc + k) * NH + c];
        }
        __syncthreads();
#pragma unroll
        for (int kk = 0; kk < 32; kk += 4) {
            float4 a[8];
#pragma unroll
            for (int i = 0; i < 8; i++) a[i] = *(const float4*)&As[yrow + i * 8][kk];
#pragma unroll
            for (int q = 0; q < 4; q++) {
                float4 b = *(const float4*)&Bs[kk + q][xcol];
#pragma unroll
                for (int i = 0; i < 8; i++) {
                    float av = (q == 0) ? a[i].x : (q == 1) ? a[i].y : (q == 2) ? a[i].z : a[i].w;
                    acc[i][0] = fmaf(av, b.x, acc[i][0]);
                    acc[i][1] = fmaf(av, b.y, acc[i][1]);
                    acc[i][2] = fmaf(av, b.z, acc[i][2]);
                    acc[i][3] = fmaf(av, b.w, acc[i][3]);
                }
            }
        }
        __syncthreads();
    }
#pragma unroll
    for (int i = 0; i < 8; i++) {
        int gr = rowbase + yrow + i * 8;
        if (gr < NN) {
            union { ushort4 u; __hip_bfloat16 h[4]; } o;
            o.h[0] = __float2bfloat16(acc[i][0]);
            o.h[1] = __float2bfloat16(acc[i][1]);
            o.h[2] = __float2bfloat16(acc[i][2]);
            o.h[3] = __float2bfloat16(acc[i][3]);
            *(ushort4*)&out[(size_t)gr * NH + xcol] = o.u;
        }
    }
}

__device__ __forceinline__ float2 bf2_unpack(unsigned int v) {
    return make_float2(__uint_as_float(v << 16), __uint_as_float(v & 0xffff0000u));
}

__device__ __forceinline__ unsigned int pack2bf(float lo, float hi) {
    unsigned int a = (unsigned int)__hip_bfloat16_raw(__float2bfloat16(lo)).x;
    unsigned int b = (unsigned int)__hip_bfloat16_raw(__float2bfloat16(hi)).x;
    return a | (b << 16);
}

// ---------------- CSR gather-aggregate (bf16 lin) + self loop + bias + relu; writes stride-384 ----------------
__global__ __launch_bounds__(256) void k_agg(const unsigned int* __restrict__ linb,
                                             const float* __restrict__ dinv,
                                             const int* __restrict__ rowptr, const int2* __restrict__ cw,
                                             const float* __restrict__ bias,
                                             float* __restrict__ outp, int do_relu) {
    int t = threadIdx.x;
    int node = blockIdx.x * 4 + (t >> 6);
    if (node >= NN) return;
    int ch = t & 63;          // packed-pair index: channels 2*ch, 2*ch+1
    int c = ch << 1;
    float di = dinv[node];
    float2 sv = bf2_unpack(linb[(size_t)node * 64 + ch]);
    float a0 = fmaf(sv.x, di * di, bias[c]);
    float a1 = fmaf(sv.y, di * di, bias[c + 1]);
    int beg = rowptr[node], end = rowptr[node + 1];
    int j = beg;
    for (; j + 1 < end; j += 2) {
        int2 p0 = cw[j];
        int2 p1 = cw[j + 1];
        unsigned int v0 = linb[(size_t)p0.x * 64 + ch];
        unsigned int v1 = linb[(size_t)p1.x * 64 + ch];
        float w0 = __int_as_float(p0.y);
        float w1 = __int_as_float(p1.y);
        float2 f0 = bf2_unpack(v0);
        float2 f1 = bf2_unpack(v1);
        a0 = fmaf(f0.x, w0, a0);
        a1 = fmaf(f0.y, w0, a1);
        a0 = fmaf(f1.x, w1, a0);
        a1 = fmaf(f1.y, w1, a1);
    }
    if (j < end) {
        int2 p = cw[j];
        unsigned int v = linb[(size_t)p.x * 64 + ch];
        float w = __int_as_float(p.y);
        float2 f = bf2_unpack(v);
        a0 = fmaf(f.x, w, a0);
        a1 = fmaf(f.y, w, a1);
    }
    if (do_relu) { a0 = fmaxf(a0, 0.f); a1 = fmaxf(a1, 0.f); }
    *(float2*)&outp[(size_t)node * 384 + c] = make_float2(a0, a1);
}

// ---------------- BN stats: per-channel sum & sumsq over stride-384 matrix ----------------
__global__ __launch_bounds__(256) void k_stats(const float* __restrict__ pre, float* __restrict__ sums) {
    int t = threadIdx.x;
    int c = t & 127, h = t >> 7;
    float s = 0.f, s2 = 0.f;
    for (int r = blockIdx.x * 2 + h; r < NN; r += gridDim.x * 2) {
        float v = pre[(size_t)r * 384 + c];
        s += v;
        s2 = fmaf(v, v, s2);
    }
    __shared__ float ls[256], ls2[256];
    ls[t] = s; ls2[t] = s2;
    __syncthreads();
    if (t < 128) {
        atomicAdd(&sums[c], ls[t] + ls[t + 128]);
        atomicAdd(&sums[NH + c], ls2[t] + ls2[t + 128]);
    }
}

// ---------------- finalize BN: scale/shift per channel ----------------
__global__ void k_bnfinal(float* __restrict__ sums, const float* __restrict__ g,
                          const float* __restrict__ beta) {
    int c = threadIdx.x;
    if (c < NH) {
        float m = sums[c] * (1.0f / NN);
        float v = sums[NH + c] * (1.0f / NN) - m * m;
        float rstd = rsqrtf(v + BN_EPS);
        float sc = g[c] * rstd;
        sums[256 + c] = sc;
        sums[384 + c] = beta[c] - m * sc;
    }
}

// ---------------- apply BN affine in place (stride-384 region) ----------------
__global__ __launch_bounds__(256) void k_bnapply(float* __restrict__ pre, const float* __restrict__ sums) {
    int idx = blockIdx.x * 256 + threadIdx.x;  // NN*64 float2's
    if (idx >= NN * 64) return;
    int n = idx >> 6, cp = (idx & 63) << 1;
    float2 sc = *(const float2*)&sums[256 + cp];
    float2 sh = *(const float2*)&sums[384 + cp];
    float2 v = *(float2*)&pre[(size_t)n * 384 + cp];
    v.x = fmaf(v.x, sc.x, sh.x);
    v.y = fmaf(v.y, sc.y, sh.y);
    *(float2*)&pre[(size_t)n * 384 + cp] = v;
}

// ---------------- final linear [NN,384]@[384,40] via MFMA + softmax ----------------
// Block = 256 thr (4 waves), 64 rows/block (16 rows/wave). Cols padded 40->48 = 3 col-tiles.
// W staged in LDS transposed: Wt[(ct*16+c)*196 + k2] = pack(bf16 W[2k2][col], bf16 W[2k2+1][col]).
// Stride 196 words == 4 mod 32 -> conflict-free b128 B-frag reads.
// A-frag: lane l holds embed[row=base+(l&15)][k=(l>>4)*8+j], rounded to bf16.
// D layout (m89): col = lane&15, row = (lane>>4)*4 + reg.
__global__ __launch_bounds__(256) void k_final(const float* __restrict__ embed,
                                               const float* __restrict__ linW,
                                               const float* __restrict__ linb,
                                               float* __restrict__ logits, float* __restrict__ probs) {
    __shared__ unsigned int Wt[3 * 16 * 196];  // 37632 B
    int t = threadIdx.x;
    for (int i = t; i < 3 * 16 * 192; i += 256) {
        int ct = i / (16 * 192);
        int rem = i - ct * (16 * 192);
        int c = rem / 192, k2 = rem - c * 192;
        int col = ct * 16 + c;
        float lo = (col < NC) ? linW[(size_t)(2 * k2) * NC + col] : 0.f;
        float hi = (col < NC) ? linW[(size_t)(2 * k2 + 1) * NC + col] : 0.f;
        Wt[(ct * 16 + c) * 196 + k2] = pack2bf(lo, hi);
    }
    __syncthreads();

    int wid = t >> 6, l = t & 63;
    int rowbase = blockIdx.x * 64 + wid * 16;
    int l15 = l & 15, lhi = l >> 4;

    int arow = rowbase + l15;
    if (arow > NN - 1) arow = NN - 1;
    const float4* ap = (const float4*)&embed[(size_t)arow * 384 + lhi * 8];

    f32x4 acc0 = {0.f, 0.f, 0.f, 0.f};
    f32x4 acc1 = {0.f, 0.f, 0.f, 0.f};
    f32x4 acc2 = {0.f, 0.f, 0.f, 0.f};

    for (int kb = 0; kb < 12; kb++) {
        float4 a0 = ap[kb * 8];
        float4 a1 = ap[kb * 8 + 1];
        union { unsigned int u[4]; bf16x8 v; } af;
        af.u[0] = pack2bf(a0.x, a0.y);
        af.u[1] = pack2bf(a0.z, a0.w);
        af.u[2] = pack2bf(a1.x, a1.y);
        af.u[3] = pack2bf(a1.z, a1.w);
        int wbase = kb * 16 + lhi * 4;
        bf16x8 b0 = *(const bf16x8*)&Wt[(0 * 16 + l15) * 196 + wbase];
        bf16x8 b1 = *(const bf16x8*)&Wt[(1 * 16 + l15) * 196 + wbase];
        bf16x8 b2 = *(const bf16x8*)&Wt[(2 * 16 + l15) * 196 + wbase];
        acc0 = __builtin_amdgcn_mfma_f32_16x16x32_bf16(af.v, b0, acc0, 0, 0, 0);
        acc1 = __builtin_amdgcn_mfma_f32_16x16x32_bf16(af.v, b1, acc1, 0, 0, 0);
        acc2 = __builtin_amdgcn_mfma_f32_16x16x32_bf16(af.v, b2, acc2, 0, 0, 0);
    }

    // bias per col-tile
    int col0 = 0 * 16 + l15, col1 = 1 * 16 + l15, col2 = 2 * 16 + l15;
    float lb0 = (col0 < NC) ? linb[col0] : 0.f;
    float lb1 = (col1 < NC) ? linb[col1] : 0.f;
    float lb2 = linb ? ((col2 < NC) ? linb[col2] : 0.f) : 0.f;

#pragma unroll
    for (int reg = 0; reg < 4; reg++) {
        int row = rowbase + lhi * 4 + reg;
        float v0 = acc0[reg] + lb0;
        float v1 = acc1[reg] + lb1;
        float v2 = acc2[reg] + lb2;
        float m = fmaxf(v0, v1);                    // cols 0..31 always valid
        if (col2 < NC) m = fmaxf(m, v2);
#pragma unroll
        for (int off = 1; off < 16; off <<= 1) m = fmaxf(m, __shfl_xor(m, off));
        float e0 = __expf(v0 - m);
        float e1 = __expf(v1 - m);
        float e2 = (col2 < NC) ? __expf(v2 - m) : 0.f;
        float s = e0 + e1 + e2;
#pragma unroll
        for (int off = 1; off < 16; off <<= 1) s += __shfl_xor(s, off);
        float inv = 1.0f / s;
        if (row < NN) {
            size_t base = (size_t)row * NC;
            logits[base + col0] = v0;
            probs[base + col0] = e0 * inv;
            logits[base + col1] = v1;
            probs[base + col1] = e1 * inv;
            if (col2 < NC) {
                logits[base + col2] = v2;
                probs[base + col2] = e2 * inv;
            }
        }
    }
}

extern "C" void kernel_launch(void* const* d_in, const int* in_sizes, int n_in,
                              void* d_out, int out_size, void* d_ws, size_t ws_size,
                              hipStream_t stream) {
    const float* x    = (const float*)d_in[0];
    const int*   ei   = (const int*)d_in[1];
    const float* ew   = (const float*)d_in[2];
    const float* W1   = (const float*)d_in[3];
    const float* b1   = (const float*)d_in[4];
    const float* g1   = (const float*)d_in[5];
    const float* be1  = (const float*)d_in[6];
    const float* W2   = (const float*)d_in[7];
    const float* b2   = (const float*)d_in[8];
    const float* g2   = (const float*)d_in[9];
    const float* be2  = (const float*)d_in[10];
    const float* W3   = (const float*)d_in[11];
    const float* b3   = (const float*)d_in[12];
    const float* g3   = (const float*)d_in[13];
    const float* be3  = (const float*)d_in[14];
    const float* linW = (const float*)d_in[15];
    const float* linb = (const float*)d_in[16];

    float* out    = (float*)d_out;
    float* logits = out;
    float* probs  = out + (size_t)NN * NC;
    float* embed  = out + (size_t)2 * NN * NC;

    char* ws = (char*)d_ws;
    size_t off = 0;
    auto alloc = [&](size_t bytes) -> char* {
        char* p = ws + off;
        off = (off + bytes + 255) & ~(size_t)255;
        return p;
    };
    float* deg    = (float*)alloc((size_t)NN * 4);
    int*   count  = (int*)alloc((size_t)NN * 4);
    int*   rowptr = (int*)alloc((size_t)(NN + 1) * 4);
    int*   fill   = (int*)alloc((size_t)NN * 4);
    int2*  cw     = (int2*)alloc((size_t)NE * 8);
    __hip_bfloat16* lin = (__hip_bfloat16*)alloc((size_t)NN * NH * 2);
    float* sums   = (float*)alloc(3 * 1024 * 4);
    (void)ws_size; (void)in_sizes; (void)n_in; (void)out_size;

    int gN = (NN + 255) / 256;
    int gE = (NE + 255) / 256;
    int gG = (NN + 63) / 64;
    int gA = (NN + 3) / 4;
    int gB = (NN * 64 + 255) / 256;
    int gF = (NN + 63) / 64;

    k_init<<<gN, 256, 0, stream>>>(deg, count, sums);
    k_edge<<<gE, 256, 0, stream>>>(ei, ew, deg, count);
    k_dinv<<<gN, 256, 0, stream>>>(deg);
    k_scan<<<1, 1024, 0, stream>>>(count, rowptr, fill);
    k_scatter<<<gE, 256, 0, stream>>>(ei, ew, deg, fill, cw);

    // layer 1
    k_gemm<NF><<<gG, 256, 0, stream>>>(x, NF, W1, lin);
    k_agg<<<gA, 256, 0, stream>>>((const unsigned int*)lin, deg, rowptr, cw, b1, embed + 0, 1);
    k_stats<<<1024, 256, 0, stream>>>(embed + 0, sums + 0);
    k_bnfinal<<<1, 128, 0, stream>>>(sums + 0, g1, be1);
    k_bnapply<<<gB, 256, 0, stream>>>(embed + 0, sums + 0);
    // layer 2
    k_gemm<NH><<<gG, 256, 0, stream>>>(embed + 0, 384, W2, lin);
    k_agg<<<gA, 256, 0, stream>>>((const unsigned int*)lin, deg, rowptr, cw, b2, embed + 128, 1);
    k_stats<<<1024, 256, 0, stream>>>(embed + 128, sums + 1024);
    k_bnfinal<<<1, 128, 0, stream>>>(sums + 1024, g2, be2);
    k_bnapply<<<gB, 256, 0, stream>>>(embed + 128, sums + 1024);
    // layer 3 (no relu)
    k_gemm<NH><<<gG, 256, 0, stream>>>(embed + 128, 384, W3, lin);
    k_agg<<<gA, 256, 0, stream>>>((const unsigned int*)lin, deg, rowptr, cw, b3, embed + 256, 0);
    k_stats<<<1024, 256, 0, stream>>>(embed + 256, sums + 2048);
    k_bnfinal<<<1, 128, 0, stream>>>(sums + 2048, g3, be3);
    k_bnapply<<<gB, 256, 0, stream>>>(embed + 256, sums + 2048);
    // final linear + softmax (MFMA)
    k_final<<<gF, 256, 0, stream>>>(embed, linW, linb, logits, probs);
}

// Round 4
// 1245.369 us; speedup vs baseline: 1.7013x; 1.2275x over previous
//
#include <hip/hip_runtime.h>
#include <hip/hip_bf16.h>
#include <math.h>

#define NN 100000
#define NE 3200000
#define NF 256
#define NH 128
#define NC 40
#define BN_EPS 1e-5f

typedef __attribute__((ext_vector_type(8))) short bf16x8;
typedef __attribute__((ext_vector_type(4))) float f32x4;

__device__ __forceinline__ float2 bf2_unpack(unsigned int v) {
    return make_float2(__uint_as_float(v << 16), __uint_as_float(v & 0xffff0000u));
}
__device__ __forceinline__ unsigned int pack2bf(float lo, float hi) {
    unsigned int a = (unsigned int)__hip_bfloat16_raw(__float2bfloat16(lo)).x;
    unsigned int b = (unsigned int)__hip_bfloat16_raw(__float2bfloat16(hi)).x;
    return a | (b << 16);
}

// ---------------- init: hist=0, sums=0 ----------------
__global__ __launch_bounds__(256) void k_init(unsigned long long* hist, float* sums) {
    int i = blockIdx.x * 256 + threadIdx.x;
    if (i < NN) hist[i] = 0ULL;
    if (i < 3 * 1024) sums[i] = 0.0f;
}

// ---------------- edge pass: ONE u64 packed atomic -> (count | 12.32 fixed weight sum) ----------------
// Return value's count field = this edge's slot within its dst row.
__global__ __launch_bounds__(256) void k_edge(const int* __restrict__ ei, const float* __restrict__ ew,
                                              unsigned long long* __restrict__ hist,
                                              int* __restrict__ pos) {
    int e = blockIdx.x * 256 + threadIdx.x;
    if (e >= NE) return;
    int d = ei[NE + e];
    float w = ew[e];
    unsigned long long pack = (1ULL << 44) | (unsigned long long)(w * 4294967296.0f);
    unsigned long long old = atomicAdd(&hist[d], pack);
    pos[e] = (int)(old >> 44);
}

// ---------------- dinv = rsqrt(1 + fixedsum * 2^-32) ----------------
__global__ __launch_bounds__(256) void k_dinv(const unsigned long long* __restrict__ hist,
                                              float* __restrict__ dinv) {
    int i = blockIdx.x * 256 + threadIdx.x;
    if (i < NN) {
        float ws = (float)(hist[i] & 0xFFFFFFFFFFFULL) * 2.3283064365386963e-10f;
        dinv[i] = rsqrtf(1.0f + ws);
    }
}

// ---------------- single-block exclusive scan of hist counts -> rowptr (4 elems/thread) ----------------
__global__ __launch_bounds__(1024) void k_scan(const unsigned long long* __restrict__ hist,
                                               int* __restrict__ rowptr) {
    __shared__ int wsum[16];
    __shared__ int s_carry;
    int t = threadIdx.x;
    int lane = t & 63, wid = t >> 6;
    if (t == 0) s_carry = 0;
    __syncthreads();
    for (int base = 0; base < NN; base += 4096) {
        int i0 = base + t * 4;
        int c[4];
#pragma unroll
        for (int j = 0; j < 4; j++) {
            int i = i0 + j;
            c[j] = (i < NN) ? (int)(hist[i] >> 44) : 0;
        }
        int v = c[0] + c[1] + c[2] + c[3];
        int x = v;
#pragma unroll
        for (int off = 1; off < 64; off <<= 1) {
            int y = __shfl_up(x, off);
            if (lane >= off) x += y;
        }
        if (lane == 63) wsum[wid] = x;
        __syncthreads();
        if (wid == 0 && lane < 16) {
            int s = wsum[lane];
#pragma unroll
            for (int off = 1; off < 16; off <<= 1) {
                int y = __shfl_up(s, off);
                if (lane >= off) s += y;
            }
            wsum[lane] = s;
        }
        __syncthreads();
        int woff = (wid > 0) ? wsum[wid - 1] : 0;
        int incl = x + woff;
        int carry = s_carry;
        int run = carry + incl - v;
#pragma unroll
        for (int j = 0; j < 4; j++) {
            int i = i0 + j;
            if (i < NN) rowptr[i] = run;
            run += c[j];
        }
        __syncthreads();
        if (t == 1023) s_carry = carry + incl;
        __syncthreads();
    }
    if (t == 0) rowptr[NN] = s_carry;
}

// ---------------- scatter edges into CSR (no atomics), norm inline ----------------
__global__ __launch_bounds__(256) void k_scatter(const int* __restrict__ ei, const float* __restrict__ ew,
                                                 const float* __restrict__ dinv,
                                                 const int* __restrict__ rowptr,
                                                 const int* __restrict__ pos,
                                                 int2* __restrict__ cw) {
    int e = blockIdx.x * 256 + threadIdx.x;
    if (e >= NE) return;
    int s = ei[e], d = ei[NE + e];
    float nv = dinv[s] * ew[e] * dinv[d];
    cw[rowptr[d] + pos[e]] = make_int2(s, __float_as_int(nv));
}

// ---------------- MFMA bf16 GEMM: out_bf16[NN,128] = H[NN,K](ld=ldh,f32) @ W[K,128] ----------------
// 128 rows/block (4 waves x 32 rows), B staged per k-step in LDS packed-pair [128][20].
// A-frag: lane l holds H[row=base+(l&15)][k=(l>>4)*8+j] rounded to bf16 (validated layout, m89).
template <int K>
__global__ __launch_bounds__(256) void k_gemm_mfma(const float* __restrict__ H, int ldh,
                                                   const float* __restrict__ W,
                                                   __hip_bfloat16* __restrict__ out) {
    __shared__ unsigned int Bt[128][20];  // 10240 B, stride 20 words (16B-aligned b128 reads)
    int t = threadIdx.x;
    int wid = t >> 6, l = t & 63;
    int l15 = l & 15, lhi = l >> 4;
    int rowbase = blockIdx.x * 128 + wid * 32;

    int ar0 = rowbase + l15;      if (ar0 >= NN) ar0 = NN - 1;
    int ar1 = rowbase + 16 + l15; if (ar1 >= NN) ar1 = NN - 1;

    f32x4 acc[2][8];
#pragma unroll
    for (int rt = 0; rt < 2; rt++)
#pragma unroll
        for (int ct = 0; ct < 8; ct++) acc[rt][ct] = (f32x4){0.f, 0.f, 0.f, 0.f};

    for (int kb = 0; kb < K / 32; kb++) {
        __syncthreads();
        for (int i = t; i < 2048; i += 256) {
            int c = i & 127, k2l = i >> 7;
            int k = kb * 32 + 2 * k2l;
            Bt[c][k2l] = pack2bf(W[(size_t)k * NH + c], W[(size_t)(k + 1) * NH + c]);
        }
        __syncthreads();
        const float4* a0p = (const float4*)&H[(size_t)ar0 * ldh + kb * 32 + lhi * 8];
        const float4* a1p = (const float4*)&H[(size_t)ar1 * ldh + kb * 32 + lhi * 8];
        float4 x0 = a0p[0], x1 = a0p[1];
        float4 y0 = a1p[0], y1 = a1p[1];
        union { unsigned int u[4]; bf16x8 v; } af0, af1;
        af0.u[0] = pack2bf(x0.x, x0.y); af0.u[1] = pack2bf(x0.z, x0.w);
        af0.u[2] = pack2bf(x1.x, x1.y); af0.u[3] = pack2bf(x1.z, x1.w);
        af1.u[0] = pack2bf(y0.x, y0.y); af1.u[1] = pack2bf(y0.z, y0.w);
        af1.u[2] = pack2bf(y1.x, y1.y); af1.u[3] = pack2bf(y1.z, y1.w);
#pragma unroll
        for (int ct = 0; ct < 8; ct++) {
            bf16x8 b = *(const bf16x8*)&Bt[ct * 16 + l15][lhi * 4];
            acc[0][ct] = __builtin_amdgcn_mfma_f32_16x16x32_bf16(af0.v, b, acc[0][ct], 0, 0, 0);
            acc[1][ct] = __builtin_amdgcn_mfma_f32_16x16x32_bf16(af1.v, b, acc[1][ct], 0, 0, 0);
        }
    }
#pragma unroll
    for (int rt = 0; rt < 2; rt++)
#pragma unroll
        for (int ct = 0; ct < 8; ct++)
#pragma unroll
            for (int reg = 0; reg < 4; reg++) {
                int row = rowbase + rt * 16 + lhi * 4 + reg;
                if (row < NN)
                    out[(size_t)row * NH + ct * 16 + l15] = __float2bfloat16(acc[rt][ct][reg]);
            }
}

// ---------------- CSR gather-aggregate (bf16 lin) + self loop + bias + relu; writes stride-384 ----------------
__global__ __launch_bounds__(256) void k_agg(const unsigned int* __restrict__ linb,
                                             const float* __restrict__ dinv,
                                             const int* __restrict__ rowptr, const int2* __restrict__ cw,
                                             const float* __restrict__ bias,
                                             float* __restrict__ outp, int do_relu) {
    int t = threadIdx.x;
    int node = blockIdx.x * 4 + (t >> 6);
    if (node >= NN) return;
    int ch = t & 63;
    int c = ch << 1;
    float di = dinv[node];
    float2 sv = bf2_unpack(linb[(size_t)node * 64 + ch]);
    float a0 = fmaf(sv.x, di * di, bias[c]);
    float a1 = fmaf(sv.y, di * di, bias[c + 1]);
    int beg = rowptr[node], end = rowptr[node + 1];
    int j = beg;
    for (; j + 1 < end; j += 2) {
        int2 p0 = cw[j];
        int2 p1 = cw[j + 1];
        unsigned int v0 = linb[(size_t)p0.x * 64 + ch];
        unsigned int v1 = linb[(size_t)p1.x * 64 + ch];
        float w0 = __int_as_float(p0.y);
        float w1 = __int_as_float(p1.y);
        float2 f0 = bf2_unpack(v0);
        float2 f1 = bf2_unpack(v1);
        a0 = fmaf(f0.x, w0, a0);
        a1 = fmaf(f0.y, w0, a1);
        a0 = fmaf(f1.x, w1, a0);
        a1 = fmaf(f1.y, w1, a1);
    }
    if (j < end) {
        int2 p = cw[j];
        unsigned int v = linb[(size_t)p.x * 64 + ch];
        float w = __int_as_float(p.y);
        float2 f = bf2_unpack(v);
        a0 = fmaf(f.x, w, a0);
        a1 = fmaf(f.y, w, a1);
    }
    if (do_relu) { a0 = fmaxf(a0, 0.f); a1 = fmaxf(a1, 0.f); }
    *(float2*)&outp[(size_t)node * 384 + c] = make_float2(a0, a1);
}

// ---------------- BN stats ----------------
__global__ __launch_bounds__(256) void k_stats(const float* __restrict__ pre, float* __restrict__ sums) {
    int t = threadIdx.x;
    int c = t & 127, h = t >> 7;
    float s = 0.f, s2 = 0.f;
    for (int r = blockIdx.x * 2 + h; r < NN; r += gridDim.x * 2) {
        float v = pre[(size_t)r * 384 + c];
        s += v;
        s2 = fmaf(v, v, s2);
    }
    __shared__ float ls[256], ls2[256];
    ls[t] = s; ls2[t] = s2;
    __syncthreads();
    if (t < 128) {
        atomicAdd(&sums[c], ls[t] + ls[t + 128]);
        atomicAdd(&sums[NH + c], ls2[t] + ls2[t + 128]);
    }
}

// ---------------- finalize BN ----------------
__global__ void k_bnfinal(float* __restrict__ sums, const float* __restrict__ g,
                          const float* __restrict__ beta) {
    int c = threadIdx.x;
    if (c < NH) {
        float m = sums[c] * (1.0f / NN);
        float v = sums[NH + c] * (1.0f / NN) - m * m;
        float rstd = rsqrtf(v + BN_EPS);
        float sc = g[c] * rstd;
        sums[256 + c] = sc;
        sums[384 + c] = beta[c] - m * sc;
    }
}

// ---------------- apply BN affine in place ----------------
__global__ __launch_bounds__(256) void k_bnapply(float* __restrict__ pre, const float* __restrict__ sums) {
    int idx = blockIdx.x * 256 + threadIdx.x;
    if (idx >= NN * 64) return;
    int n = idx >> 6, cp = (idx & 63) << 1;
    float2 sc = *(const float2*)&sums[256 + cp];
    float2 sh = *(const float2*)&sums[384 + cp];
    float2 v = *(float2*)&pre[(size_t)n * 384 + cp];
    v.x = fmaf(v.x, sc.x, sh.x);
    v.y = fmaf(v.y, sc.y, sh.y);
    *(float2*)&pre[(size_t)n * 384 + cp] = v;
}

// ---------------- final linear [NN,384]@[384,40] via MFMA + softmax ----------------
__global__ __launch_bounds__(256) void k_final(const float* __restrict__ embed,
                                               const float* __restrict__ linW,
                                               const float* __restrict__ linb,
                                               float* __restrict__ logits, float* __restrict__ probs) {
    __shared__ unsigned int Wt[3 * 16 * 196];  // 37632 B
    int t = threadIdx.x;
    for (int i = t; i < 3 * 16 * 192; i += 256) {
        int ct = i / (16 * 192);
        int rem = i - ct * (16 * 192);
        int c = rem / 192, k2 = rem - c * 192;
        int col = ct * 16 + c;
        float lo = (col < NC) ? linW[(size_t)(2 * k2) * NC + col] : 0.f;
        float hi = (col < NC) ? linW[(size_t)(2 * k2 + 1) * NC + col] : 0.f;
        Wt[(ct * 16 + c) * 196 + k2] = pack2bf(lo, hi);
    }
    __syncthreads();

    int wid = t >> 6, l = t & 63;
    int rowbase = blockIdx.x * 64 + wid * 16;
    int l15 = l & 15, lhi = l >> 4;

    int arow = rowbase + l15;
    if (arow > NN - 1) arow = NN - 1;
    const float4* ap = (const float4*)&embed[(size_t)arow * 384 + lhi * 8];

    f32x4 acc0 = {0.f, 0.f, 0.f, 0.f};
    f32x4 acc1 = {0.f, 0.f, 0.f, 0.f};
    f32x4 acc2 = {0.f, 0.f, 0.f, 0.f};

    for (int kb = 0; kb < 12; kb++) {
        float4 a0 = ap[kb * 8];
        float4 a1 = ap[kb * 8 + 1];
        union { unsigned int u[4]; bf16x8 v; } af;
        af.u[0] = pack2bf(a0.x, a0.y);
        af.u[1] = pack2bf(a0.z, a0.w);
        af.u[2] = pack2bf(a1.x, a1.y);
        af.u[3] = pack2bf(a1.z, a1.w);
        int wbase = kb * 16 + lhi * 4;
        bf16x8 b0 = *(const bf16x8*)&Wt[(0 * 16 + l15) * 196 + wbase];
        bf16x8 b1 = *(const bf16x8*)&Wt[(1 * 16 + l15) * 196 + wbase];
        bf16x8 b2 = *(const bf16x8*)&Wt[(2 * 16 + l15) * 196 + wbase];
        acc0 = __builtin_amdgcn_mfma_f32_16x16x32_bf16(af.v, b0, acc0, 0, 0, 0);
        acc1 = __builtin_amdgcn_mfma_f32_16x16x32_bf16(af.v, b1, acc1, 0, 0, 0);
        acc2 = __builtin_amdgcn_mfma_f32_16x16x32_bf16(af.v, b2, acc2, 0, 0, 0);
    }

    int col0 = 0 * 16 + l15, col1 = 1 * 16 + l15, col2 = 2 * 16 + l15;
    float lb0 = (col0 < NC) ? linb[col0] : 0.f;
    float lb1 = (col1 < NC) ? linb[col1] : 0.f;
    float lb2 = (col2 < NC) ? linb[col2] : 0.f;

#pragma unroll
    for (int reg = 0; reg < 4; reg++) {
        int row = rowbase + lhi * 4 + reg;
        float v0 = acc0[reg] + lb0;
        float v1 = acc1[reg] + lb1;
        float v2 = acc2[reg] + lb2;
        float m = fmaxf(v0, v1);
        if (col2 < NC) m = fmaxf(m, v2);
#pragma unroll
        for (int off = 1; off < 16; off <<= 1) m = fmaxf(m, __shfl_xor(m, off));
        float e0 = __expf(v0 - m);
        float e1 = __expf(v1 - m);
        float e2 = (col2 < NC) ? __expf(v2 - m) : 0.f;
        float s = e0 + e1 + e2;
#pragma unroll
        for (int off = 1; off < 16; off <<= 1) s += __shfl_xor(s, off);
        float inv = 1.0f / s;
        if (row < NN) {
            size_t base = (size_t)row * NC;
            logits[base + col0] = v0;
            probs[base + col0] = e0 * inv;
            logits[base + col1] = v1;
            probs[base + col1] = e1 * inv;
            if (col2 < NC) {
                logits[base + col2] = v2;
                probs[base + col2] = e2 * inv;
            }
        }
    }
}

extern "C" void kernel_launch(void* const* d_in, const int* in_sizes, int n_in,
                              void* d_out, int out_size, void* d_ws, size_t ws_size,
                              hipStream_t stream) {
    const float* x    = (const float*)d_in[0];
    const int*   ei   = (const int*)d_in[1];
    const float* ew   = (const float*)d_in[2];
    const float* W1   = (const float*)d_in[3];
    const float* b1   = (const float*)d_in[4];
    const float* g1   = (const float*)d_in[5];
    const float* be1  = (const float*)d_in[6];
    const float* W2   = (const float*)d_in[7];
    const float* b2   = (const float*)d_in[8];
    const float* g2   = (const float*)d_in[9];
    const float* be2  = (const float*)d_in[10];
    const float* W3   = (const float*)d_in[11];
    const float* b3   = (const float*)d_in[12];
    const float* g3   = (const float*)d_in[13];
    const float* be3  = (const float*)d_in[14];
    const float* linW = (const float*)d_in[15];
    const float* linb = (const float*)d_in[16];

    float* out    = (float*)d_out;
    float* logits = out;
    float* probs  = out + (size_t)NN * NC;
    float* embed  = out + (size_t)2 * NN * NC;

    char* ws = (char*)d_ws;
    size_t off = 0;
    auto alloc = [&](size_t bytes) -> char* {
        char* p = ws + off;
        off = (off + bytes + 255) & ~(size_t)255;
        return p;
    };
    float*              dinv   = (float*)alloc((size_t)NN * 4);
    unsigned long long* hist   = (unsigned long long*)alloc((size_t)NN * 8);
    int*                rowptr = (int*)alloc((size_t)(NN + 1) * 4);
    int2*               cw     = (int2*)alloc((size_t)NE * 8);
    __hip_bfloat16*     lin    = (__hip_bfloat16*)alloc((size_t)NN * NH * 2);
    float*              sums   = (float*)alloc(3 * 1024 * 4);
    int*                pos    = (int*)lin;  // alias: pos dead before lin first written
    (void)ws_size; (void)in_sizes; (void)n_in; (void)out_size;

    int gN = (NN + 255) / 256;
    int gE = (NE + 255) / 256;
    int gM = (NN + 127) / 128;
    int gA = (NN + 3) / 4;
    int gB = (NN * 64 + 255) / 256;
    int gF = (NN + 63) / 64;

    k_init<<<gN, 256, 0, stream>>>(hist, sums);
    k_edge<<<gE, 256, 0, stream>>>(ei, ew, hist, pos);
    k_dinv<<<gN, 256, 0, stream>>>(hist, dinv);
    k_scan<<<1, 1024, 0, stream>>>(hist, rowptr);
    k_scatter<<<gE, 256, 0, stream>>>(ei, ew, dinv, rowptr, pos, cw);

    // layer 1
    k_gemm_mfma<NF><<<gM, 256, 0, stream>>>(x, NF, W1, lin);
    k_agg<<<gA, 256, 0, stream>>>((const unsigned int*)lin, dinv, rowptr, cw, b1, embed + 0, 1);
    k_stats<<<1024, 256, 0, stream>>>(embed + 0, sums + 0);
    k_bnfinal<<<1, 128, 0, stream>>>(sums + 0, g1, be1);
    k_bnapply<<<gB, 256, 0, stream>>>(embed + 0, sums + 0);
    // layer 2
    k_gemm_mfma<NH><<<gM, 256, 0, stream>>>(embed + 0, 384, W2, lin);
    k_agg<<<gA, 256, 0, stream>>>((const unsigned int*)lin, dinv, rowptr, cw, b2, embed + 128, 1);
    k_stats<<<1024, 256, 0, stream>>>(embed + 128, sums + 1024);
    k_bnfinal<<<1, 128, 0, stream>>>(sums + 1024, g2, be2);
    k_bnapply<<<gB, 256, 0, stream>>>(embed + 128, sums + 1024);
    // layer 3 (no relu)
    k_gemm_mfma<NH><<<gM, 256, 0, stream>>>(embed + 128, 384, W3, lin);
    k_agg<<<gA, 256, 0, stream>>>((const unsigned int*)lin, dinv, rowptr, cw, b3, embed + 256, 0);
    k_stats<<<1024, 256, 0, stream>>>(embed + 256, sums + 2048);
    k_bnfinal<<<1, 128, 0, stream>>>(sums + 2048, g3, be3);
    k_bnapply<<<gB, 256, 0, stream>>>(embed + 256, sums + 2048);
    // final linear + softmax (MFMA)
    k_final<<<gF, 256, 0, stream>>>(embed, linW, linb, logits, probs);
}

// Round 5
// 1065.970 us; speedup vs baseline: 1.9877x; 1.1683x over previous
//
#include <hip/hip_runtime.h>
#include <hip/hip_bf16.h>
#include <math.h>

#define NN 100000
#define NE 3200000
#define NF 256
#define NH 128
#define NC 40
#define BN_EPS 1e-5f

typedef __attribute__((ext_vector_type(8))) short bf16x8;
typedef __attribute__((ext_vector_type(4))) float f32x4;

__device__ __forceinline__ float2 bf2_unpack(unsigned int v) {
    return make_float2(__uint_as_float(v << 16), __uint_as_float(v & 0xffff0000u));
}
__device__ __forceinline__ unsigned int pack2bf(float lo, float hi) {
    unsigned int a = (unsigned int)__hip_bfloat16_raw(__float2bfloat16(lo)).x;
    unsigned int b = (unsigned int)__hip_bfloat16_raw(__float2bfloat16(hi)).x;
    return a | (b << 16);
}

// ---------------- init: hist=0, sums=0 ----------------
__global__ __launch_bounds__(256) void k_init(unsigned long long* hist, float* sums) {
    int i = blockIdx.x * 256 + threadIdx.x;
    if (i < NN) hist[i] = 0ULL;
    if (i < 3 * 1024) sums[i] = 0.0f;
}

// ---------------- edge pass: ONE u64 packed atomic -> (count | 12.32 fixed weight sum) ----------------
__global__ __launch_bounds__(256) void k_edge(const int* __restrict__ ei, const float* __restrict__ ew,
                                              unsigned long long* __restrict__ hist,
                                              int* __restrict__ pos) {
    int e = blockIdx.x * 256 + threadIdx.x;
    if (e >= NE) return;
    int d = ei[NE + e];
    float w = ew[e];
    unsigned long long pack = (1ULL << 44) | (unsigned long long)(w * 4294967296.0f);
    unsigned long long old = atomicAdd(&hist[d], pack);
    pos[e] = (int)(old >> 44);
}

// ---------------- dinv = rsqrt(1 + fixedsum * 2^-32) ----------------
__global__ __launch_bounds__(256) void k_dinv(const unsigned long long* __restrict__ hist,
                                              float* __restrict__ dinv) {
    int i = blockIdx.x * 256 + threadIdx.x;
    if (i < NN) {
        float ws = (float)(hist[i] & 0xFFFFFFFFFFFULL) * 2.3283064365386963e-10f;
        dinv[i] = rsqrtf(1.0f + ws);
    }
}

// ---------------- single-block exclusive scan of hist counts -> rowptr (4 elems/thread) ----------------
__global__ __launch_bounds__(1024) void k_scan(const unsigned long long* __restrict__ hist,
                                               int* __restrict__ rowptr) {
    __shared__ int wsum[16];
    __shared__ int s_carry;
    int t = threadIdx.x;
    int lane = t & 63, wid = t >> 6;
    if (t == 0) s_carry = 0;
    __syncthreads();
    for (int base = 0; base < NN; base += 4096) {
        int i0 = base + t * 4;
        int c[4];
#pragma unroll
        for (int j = 0; j < 4; j++) {
            int i = i0 + j;
            c[j] = (i < NN) ? (int)(hist[i] >> 44) : 0;
        }
        int v = c[0] + c[1] + c[2] + c[3];
        int x = v;
#pragma unroll
        for (int off = 1; off < 64; off <<= 1) {
            int y = __shfl_up(x, off);
            if (lane >= off) x += y;
        }
        if (lane == 63) wsum[wid] = x;
        __syncthreads();
        if (wid == 0 && lane < 16) {
            int s = wsum[lane];
#pragma unroll
            for (int off = 1; off < 16; off <<= 1) {
                int y = __shfl_up(s, off);
                if (lane >= off) s += y;
            }
            wsum[lane] = s;
        }
        __syncthreads();
        int woff = (wid > 0) ? wsum[wid - 1] : 0;
        int incl = x + woff;
        int carry = s_carry;
        int run = carry + incl - v;
#pragma unroll
        for (int j = 0; j < 4; j++) {
            int i = i0 + j;
            if (i < NN) rowptr[i] = run;
            run += c[j];
        }
        __syncthreads();
        if (t == 1023) s_carry = carry + incl;
        __syncthreads();
    }
    if (t == 0) rowptr[NN] = s_carry;
}

// ---------------- scatter edges into CSR (no atomics), norm inline ----------------
__global__ __launch_bounds__(256) void k_scatter(const int* __restrict__ ei, const float* __restrict__ ew,
                                                 const float* __restrict__ dinv,
                                                 const int* __restrict__ rowptr,
                                                 const int* __restrict__ pos,
                                                 int2* __restrict__ cw) {
    int e = blockIdx.x * 256 + threadIdx.x;
    if (e >= NE) return;
    int s = ei[e], d = ei[NE + e];
    float nv = dinv[s] * ew[e] * dinv[d];
    cw[rowptr[d] + pos[e]] = make_int2(s, __float_as_int(nv));
}

// ---------------- MFMA bf16 GEMM: out_bf16[NN,128] = H[NN,K](ld=ldh,f32) @ W[K,128] ----------------
template <int K>
__global__ __launch_bounds__(256) void k_gemm_mfma(const float* __restrict__ H, int ldh,
                                                   const float* __restrict__ W,
                                                   __hip_bfloat16* __restrict__ out) {
    __shared__ unsigned int Bt[128][20];  // 10240 B
    int t = threadIdx.x;
    int wid = t >> 6, l = t & 63;
    int l15 = l & 15, lhi = l >> 4;
    int rowbase = blockIdx.x * 128 + wid * 32;

    int ar0 = rowbase + l15;      if (ar0 >= NN) ar0 = NN - 1;
    int ar1 = rowbase + 16 + l15; if (ar1 >= NN) ar1 = NN - 1;

    f32x4 acc[2][8];
#pragma unroll
    for (int rt = 0; rt < 2; rt++)
#pragma unroll
        for (int ct = 0; ct < 8; ct++) acc[rt][ct] = (f32x4){0.f, 0.f, 0.f, 0.f};

    for (int kb = 0; kb < K / 32; kb++) {
        __syncthreads();
        for (int i = t; i < 2048; i += 256) {
            int c = i & 127, k2l = i >> 7;
            int k = kb * 32 + 2 * k2l;
            Bt[c][k2l] = pack2bf(W[(size_t)k * NH + c], W[(size_t)(k + 1) * NH + c]);
        }
        __syncthreads();
        const float4* a0p = (const float4*)&H[(size_t)ar0 * ldh + kb * 32 + lhi * 8];
        const float4* a1p = (const float4*)&H[(size_t)ar1 * ldh + kb * 32 + lhi * 8];
        float4 x0 = a0p[0], x1 = a0p[1];
        float4 y0 = a1p[0], y1 = a1p[1];
        union { unsigned int u[4]; bf16x8 v; } af0, af1;
        af0.u[0] = pack2bf(x0.x, x0.y); af0.u[1] = pack2bf(x0.z, x0.w);
        af0.u[2] = pack2bf(x1.x, x1.y); af0.u[3] = pack2bf(x1.z, x1.w);
        af1.u[0] = pack2bf(y0.x, y0.y); af1.u[1] = pack2bf(y0.z, y0.w);
        af1.u[2] = pack2bf(y1.x, y1.y); af1.u[3] = pack2bf(y1.z, y1.w);
#pragma unroll
        for (int ct = 0; ct < 8; ct++) {
            bf16x8 b = *(const bf16x8*)&Bt[ct * 16 + l15][lhi * 4];
            acc[0][ct] = __builtin_amdgcn_mfma_f32_16x16x32_bf16(af0.v, b, acc[0][ct], 0, 0, 0);
            acc[1][ct] = __builtin_amdgcn_mfma_f32_16x16x32_bf16(af1.v, b, acc[1][ct], 0, 0, 0);
        }
    }
#pragma unroll
    for (int rt = 0; rt < 2; rt++)
#pragma unroll
        for (int ct = 0; ct < 8; ct++)
#pragma unroll
            for (int reg = 0; reg < 4; reg++) {
                int row = rowbase + rt * 16 + lhi * 4 + reg;
                if (row < NN)
                    out[(size_t)row * NH + ct * 16 + l15] = __float2bfloat16(acc[rt][ct][reg]);
            }
}

// ---------------- CSR gather-aggregate (bf16 lin), 8-deep gather pipeline ----------------
__global__ __launch_bounds__(256) void k_agg(const unsigned int* __restrict__ linb,
                                             const float* __restrict__ dinv,
                                             const int* __restrict__ rowptr, const int2* __restrict__ cw,
                                             const float* __restrict__ bias,
                                             float* __restrict__ outp, int do_relu) {
    int t = threadIdx.x;
    int node = blockIdx.x * 4 + (t >> 6);
    if (node >= NN) return;
    int ch = t & 63;
    int c = ch << 1;
    float di = dinv[node];
    float2 sv = bf2_unpack(linb[(size_t)node * 64 + ch]);
    float a0 = fmaf(sv.x, di * di, bias[c]);
    float a1 = fmaf(sv.y, di * di, bias[c + 1]);
    int beg = rowptr[node], end = rowptr[node + 1];
    int j = beg;
    for (; j + 8 <= end; j += 8) {
        int2 p[8];
#pragma unroll
        for (int q = 0; q < 8; q++) p[q] = cw[j + q];
        unsigned int v[8];
#pragma unroll
        for (int q = 0; q < 8; q++) v[q] = linb[(size_t)(unsigned)p[q].x * 64 + ch];
#pragma unroll
        for (int q = 0; q < 8; q++) {
            float w = __int_as_float(p[q].y);
            float2 f = bf2_unpack(v[q]);
            a0 = fmaf(f.x, w, a0);
            a1 = fmaf(f.y, w, a1);
        }
    }
    for (; j < end; j++) {
        int2 p = cw[j];
        unsigned int vv = linb[(size_t)p.x * 64 + ch];
        float w = __int_as_float(p.y);
        float2 f = bf2_unpack(vv);
        a0 = fmaf(f.x, w, a0);
        a1 = fmaf(f.y, w, a1);
    }
    if (do_relu) { a0 = fmaxf(a0, 0.f); a1 = fmaxf(a1, 0.f); }
    *(float2*)&outp[(size_t)node * 384 + c] = make_float2(a0, a1);
}

// ---------------- BN stats ----------------
__global__ __launch_bounds__(256) void k_stats(const float* __restrict__ pre, float* __restrict__ sums) {
    int t = threadIdx.x;
    int c = t & 127, h = t >> 7;
    float s = 0.f, s2 = 0.f;
    for (int r = blockIdx.x * 2 + h; r < NN; r += gridDim.x * 2) {
        float v = pre[(size_t)r * 384 + c];
        s += v;
        s2 = fmaf(v, v, s2);
    }
    __shared__ float ls[256], ls2[256];
    ls[t] = s; ls2[t] = s2;
    __syncthreads();
    if (t < 128) {
        atomicAdd(&sums[c], ls[t] + ls[t + 128]);
        atomicAdd(&sums[NH + c], ls2[t] + ls2[t + 128]);
    }
}

// ---------------- finalize BN ----------------
__global__ void k_bnfinal(float* __restrict__ sums, const float* __restrict__ g,
                          const float* __restrict__ beta) {
    int c = threadIdx.x;
    if (c < NH) {
        float m = sums[c] * (1.0f / NN);
        float v = sums[NH + c] * (1.0f / NN) - m * m;
        float rstd = rsqrtf(v + BN_EPS);
        float sc = g[c] * rstd;
        sums[256 + c] = sc;
        sums[384 + c] = beta[c] - m * sc;
    }
}

// ---------------- apply BN affine in place ----------------
__global__ __launch_bounds__(256) void k_bnapply(float* __restrict__ pre, const float* __restrict__ sums) {
    int idx = blockIdx.x * 256 + threadIdx.x;
    if (idx >= NN * 64) return;
    int n = idx >> 6, cp = (idx & 63) << 1;
    float2 sc = *(const float2*)&sums[256 + cp];
    float2 sh = *(const float2*)&sums[384 + cp];
    float2 v = *(float2*)&pre[(size_t)n * 384 + cp];
    v.x = fmaf(v.x, sc.x, sh.x);
    v.y = fmaf(v.y, sc.y, sh.y);
    *(float2*)&pre[(size_t)n * 384 + cp] = v;
}

// ---------------- final linear [NN,384]@[384,40] via MFMA + softmax ----------------
__global__ __launch_bounds__(256) void k_final(const float* __restrict__ embed,
                                               const float* __restrict__ linW,
                                               const float* __restrict__ linb,
                                               float* __restrict__ logits, float* __restrict__ probs) {
    __shared__ unsigned int Wt[3 * 16 * 196];  // 37632 B
    int t = threadIdx.x;
    for (int i = t; i < 3 * 16 * 192; i += 256) {
        int ct = i / (16 * 192);
        int rem = i - ct * (16 * 192);
        int c = rem / 192, k2 = rem - c * 192;
        int col = ct * 16 + c;
        float lo = (col < NC) ? linW[(size_t)(2 * k2) * NC + col] : 0.f;
        float hi = (col < NC) ? linW[(size_t)(2 * k2 + 1) * NC + col] : 0.f;
        Wt[(ct * 16 + c) * 196 + k2] = pack2bf(lo, hi);
    }
    __syncthreads();

    int wid = t >> 6, l = t & 63;
    int rowbase = blockIdx.x * 64 + wid * 16;
    int l15 = l & 15, lhi = l >> 4;

    int arow = rowbase + l15;
    if (arow > NN - 1) arow = NN - 1;
    const float4* ap = (const float4*)&embed[(size_t)arow * 384 + lhi * 8];

    f32x4 acc0 = {0.f, 0.f, 0.f, 0.f};
    f32x4 acc1 = {0.f, 0.f, 0.f, 0.f};
    f32x4 acc2 = {0.f, 0.f, 0.f, 0.f};

    for (int kb = 0; kb < 12; kb++) {
        float4 a0 = ap[kb * 8];
        float4 a1 = ap[kb * 8 + 1];
        union { unsigned int u[4]; bf16x8 v; } af;
        af.u[0] = pack2bf(a0.x, a0.y);
        af.u[1] = pack2bf(a0.z, a0.w);
        af.u[2] = pack2bf(a1.x, a1.y);
        af.u[3] = pack2bf(a1.z, a1.w);
        int wbase = kb * 16 + lhi * 4;
        bf16x8 b0 = *(const bf16x8*)&Wt[(0 * 16 + l15) * 196 + wbase];
        bf16x8 b1 = *(const bf16x8*)&Wt[(1 * 16 + l15) * 196 + wbase];
        bf16x8 b2 = *(const bf16x8*)&Wt[(2 * 16 + l15) * 196 + wbase];
        acc0 = __builtin_amdgcn_mfma_f32_16x16x32_bf16(af.v, b0, acc0, 0, 0, 0);
        acc1 = __builtin_amdgcn_mfma_f32_16x16x32_bf16(af.v, b1, acc1, 0, 0, 0);
        acc2 = __builtin_amdgcn_mfma_f32_16x16x32_bf16(af.v, b2, acc2, 0, 0, 0);
    }

    int col0 = 0 * 16 + l15, col1 = 1 * 16 + l15, col2 = 2 * 16 + l15;
    float lb0 = (col0 < NC) ? linb[col0] : 0.f;
    float lb1 = (col1 < NC) ? linb[col1] : 0.f;
    float lb2 = (col2 < NC) ? linb[col2] : 0.f;

#pragma unroll
    for (int reg = 0; reg < 4; reg++) {
        int row = rowbase + lhi * 4 + reg;
        float v0 = acc0[reg] + lb0;
        float v1 = acc1[reg] + lb1;
        float v2 = acc2[reg] + lb2;
        float m = fmaxf(v0, v1);
        if (col2 < NC) m = fmaxf(m, v2);
#pragma unroll
        for (int off = 1; off < 16; off <<= 1) m = fmaxf(m, __shfl_xor(m, off));
        float e0 = __expf(v0 - m);
        float e1 = __expf(v1 - m);
        float e2 = (col2 < NC) ? __expf(v2 - m) : 0.f;
        float s = e0 + e1 + e2;
#pragma unroll
        for (int off = 1; off < 16; off <<= 1) s += __shfl_xor(s, off);
        float inv = 1.0f / s;
        if (row < NN) {
            size_t base = (size_t)row * NC;
            logits[base + col0] = v0;
            probs[base + col0] = e0 * inv;
            logits[base + col1] = v1;
            probs[base + col1] = e1 * inv;
            if (col2 < NC) {
                logits[base + col2] = v2;
                probs[base + col2] = e2 * inv;
            }
        }
    }
}

extern "C" void kernel_launch(void* const* d_in, const int* in_sizes, int n_in,
                              void* d_out, int out_size, void* d_ws, size_t ws_size,
                              hipStream_t stream) {
    const float* x    = (const float*)d_in[0];
    const int*   ei   = (const int*)d_in[1];
    const float* ew   = (const float*)d_in[2];
    const float* W1   = (const float*)d_in[3];
    const float* b1   = (const float*)d_in[4];
    const float* g1   = (const float*)d_in[5];
    const float* be1  = (const float*)d_in[6];
    const float* W2   = (const float*)d_in[7];
    const float* b2   = (const float*)d_in[8];
    const float* g2   = (const float*)d_in[9];
    const float* be2  = (const float*)d_in[10];
    const float* W3   = (const float*)d_in[11];
    const float* b3   = (const float*)d_in[12];
    const float* g3   = (const float*)d_in[13];
    const float* be3  = (const float*)d_in[14];
    const float* linW = (const float*)d_in[15];
    const float* linb = (const float*)d_in[16];

    float* out    = (float*)d_out;
    float* logits = out;
    float* probs  = out + (size_t)NN * NC;
    float* embed  = out + (size_t)2 * NN * NC;

    char* ws = (char*)d_ws;
    size_t off = 0;
    auto alloc = [&](size_t bytes) -> char* {
        char* p = ws + off;
        off = (off + bytes + 255) & ~(size_t)255;
        return p;
    };
    float*              dinv   = (float*)alloc((size_t)NN * 4);
    unsigned long long* hist   = (unsigned long long*)alloc((size_t)NN * 8);
    int*                rowptr = (int*)alloc((size_t)(NN + 1) * 4);
    int2*               cw     = (int2*)alloc((size_t)NE * 8);
    __hip_bfloat16*     lin    = (__hip_bfloat16*)alloc((size_t)NN * NH * 2);
    float*              sums   = (float*)alloc(3 * 1024 * 4);
    int*                pos    = (int*)lin;  // alias: pos dead before lin first written
    (void)ws_size; (void)in_sizes; (void)n_in; (void)out_size;

    int gN = (NN + 255) / 256;
    int gE = (NE + 255) / 256;
    int gM = (NN + 127) / 128;
    int gA = (NN + 3) / 4;
    int gB = (NN * 64 + 255) / 256;
    int gF = (NN + 63) / 64;

    k_init<<<gN, 256, 0, stream>>>(hist, sums);
    k_edge<<<gE, 256, 0, stream>>>(ei, ew, hist, pos);
    k_dinv<<<gN, 256, 0, stream>>>(hist, dinv);
    k_scan<<<1, 1024, 0, stream>>>(hist, rowptr);
    k_scatter<<<gE, 256, 0, stream>>>(ei, ew, dinv, rowptr, pos, cw);

    // layer 1
    k_gemm_mfma<NF><<<gM, 256, 0, stream>>>(x, NF, W1, lin);
    k_agg<<<gA, 256, 0, stream>>>((const unsigned int*)lin, dinv, rowptr, cw, b1, embed + 0, 1);
    k_stats<<<1024, 256, 0, stream>>>(embed + 0, sums + 0);
    k_bnfinal<<<1, 128, 0, stream>>>(sums + 0, g1, be1);
    k_bnapply<<<gB, 256, 0, stream>>>(embed + 0, sums + 0);
    // layer 2
    k_gemm_mfma<NH><<<gM, 256, 0, stream>>>(embed + 0, 384, W2, lin);
    k_agg<<<gA, 256, 0, stream>>>((const unsigned int*)lin, dinv, rowptr, cw, b2, embed + 128, 1);
    k_stats<<<1024, 256, 0, stream>>>(embed + 128, sums + 1024);
    k_bnfinal<<<1, 128, 0, stream>>>(sums + 1024, g2, be2);
    k_bnapply<<<gB, 256, 0, stream>>>(embed + 128, sums + 1024);
    // layer 3 (no relu)
    k_gemm_mfma<NH><<<gM, 256, 0, stream>>>(embed + 128, 384, W3, lin);
    k_agg<<<gA, 256, 0, stream>>>((const unsigned int*)lin, dinv, rowptr, cw, b3, embed + 256, 0);
    k_stats<<<1024, 256, 0, stream>>>(embed + 256, sums + 2048);
    k_bnfinal<<<1, 128, 0, stream>>>(sums + 2048, g3, be3);
    k_bnapply<<<gB, 256, 0, stream>>>(embed + 256, sums + 2048);
    // final linear + softmax (MFMA)
    k_final<<<gF, 256, 0, stream>>>(embed, linW, linb, logits, probs);
}